// Round 1
// baseline (127.142 us; speedup 1.0000x reference)
//
#include <hip/hip_runtime.h>
#include <math.h>

#define N_NODES 30000
#define K_NBR   16
#define C_IN    256
#define C_OUT   128
#define KS      9
#define S_MB    17   // K+1 mailbox slots

#define BR 32        // rows per block (GEMM)
#define CK 32        // k-chunk (GEMM)

// ---------------------------------------------------------------------------
// Per-channel constants:
//   Ws[d] = sum_s weight[d, idx[s]]
//   P[d]  = sum_s pe[idx[s], d]
//   Cd[d] = Ws[d]*((K+1)*b_lin[d] + P[d]) + bias[d] + b_res[d]
// idx[s] = floor(s * 9/17), pe[p,2j]=sin(p*10000^(-2j/128)), pe[p,2j+1]=cos(...)
// ---------------------------------------------------------------------------
__global__ void pcg_consts(const float* __restrict__ weight,
                           const float* __restrict__ b_lin,
                           const float* __restrict__ bias,
                           const float* __restrict__ b_res,
                           float* __restrict__ Ws,
                           float* __restrict__ Cd) {
    int d = threadIdx.x;
    if (d >= C_OUT) return;
    float freq = powf(10000.0f, -(float)(d & ~1) / (float)C_OUT);
    float ws = 0.f, p = 0.f;
    for (int s = 0; s < S_MB; ++s) {
        int idx = (int)floorf((float)s * (9.0f / 17.0f));
        ws += weight[d * KS + idx];
        float ang = (float)idx * freq;
        p += (d & 1) ? cosf(ang) : sinf(ang);
    }
    Ws[d] = ws;
    Cd[d] = ws * ((float)(K_NBR + 1) * b_lin[d] + p) + bias[d] + b_res[d];
}

// ---------------------------------------------------------------------------
// Fused dual GEMM: G[n,d] = ndata[n,:] . W_lin[d,:]   (no bias)
//                  out[n,d] = Ws[d]*G[n,d] + ndata[n,:].W_res[d,:] + Cd[d]
// Block: 256 threads -> 32 rows x 128 cols. Each thread: 16 rows x 1 col.
// LDS: A transposed [c][r] (broadcast float4 reads), W in [d][c] with
// XOR-swizzle (c ^ (d&31)) -> conflict-free reads and 2-way-free writes.
// ---------------------------------------------------------------------------
__global__ __launch_bounds__(256, 4)
void pcg_gemm(const float* __restrict__ ndata,
              const float* __restrict__ W_lin,
              const float* __restrict__ W_res,
              const float* __restrict__ Ws,
              const float* __restrict__ Cd,
              float* __restrict__ G,
              float* __restrict__ out) {
    __shared__ __align__(16) float sA[CK][BR + 4];   // [c][r], pad keeps f4 align
    __shared__ __align__(16) float sWl[C_OUT][CK];   // [d][c ^ (d&31)]
    __shared__ __align__(16) float sWr[C_OUT][CK];

    const int t  = threadIdx.x;
    const int n0 = blockIdx.x * BR;
    const int d  = t & (C_OUT - 1);
    const int rg = t >> 7;          // row group: rows rg*16 .. rg*16+15
    const int md = d & 31;

    float accG[16], accR[16];
#pragma unroll
    for (int i = 0; i < 16; ++i) { accG[i] = 0.f; accR[i] = 0.f; }

    for (int c0 = 0; c0 < C_IN; c0 += CK) {
        // --- stage A tile (transposed) ---
        {
            const int r = t >> 3;       // 0..31
            const int q = t & 7;        // float4 column index
            float4 v = make_float4(0.f, 0.f, 0.f, 0.f);
            if (n0 + r < N_NODES)
                v = *reinterpret_cast<const float4*>(
                        &ndata[(size_t)(n0 + r) * C_IN + c0 + q * 4]);
            sA[q * 4 + 0][r] = v.x;
            sA[q * 4 + 1][r] = v.y;
            sA[q * 4 + 2][r] = v.z;
            sA[q * 4 + 3][r] = v.w;
        }
        // --- stage W tiles (both matrices), XOR-swizzled columns ---
#pragma unroll
        for (int p = 0; p < 4; ++p) {
            const int dw = (t >> 3) + p * 32;   // 0..127
            const int cb = (t & 7) * 4;
            const int m  = dw & 31;
            float4 vl = *reinterpret_cast<const float4*>(
                            &W_lin[(size_t)dw * C_IN + c0 + cb]);
            float4 vr = *reinterpret_cast<const float4*>(
                            &W_res[(size_t)dw * C_IN + c0 + cb]);
            float al[4] = {vl.x, vl.y, vl.z, vl.w};
            float ar[4] = {vr.x, vr.y, vr.z, vr.w};
#pragma unroll
            for (int j = 0; j < 4; ++j) {
                sWl[dw][(cb + j) ^ m] = al[j];
                sWr[dw][(cb + j) ^ m] = ar[j];
            }
        }
        __syncthreads();

        // --- compute ---
#pragma unroll
        for (int c = 0; c < CK; ++c) {
            const float wl = sWl[d][c ^ md];
            const float wr = sWr[d][c ^ md];
#pragma unroll
            for (int i4 = 0; i4 < 4; ++i4) {
                const float4 a = *reinterpret_cast<const float4*>(
                                     &sA[c][rg * 16 + i4 * 4]);
                accG[i4 * 4 + 0] += a.x * wl;  accR[i4 * 4 + 0] += a.x * wr;
                accG[i4 * 4 + 1] += a.y * wl;  accR[i4 * 4 + 1] += a.y * wr;
                accG[i4 * 4 + 2] += a.z * wl;  accR[i4 * 4 + 2] += a.z * wr;
                accG[i4 * 4 + 3] += a.w * wl;  accR[i4 * 4 + 3] += a.w * wr;
            }
        }
        __syncthreads();
    }

    const float wsd = Ws[d];
    const float cdd = Cd[d];
#pragma unroll
    for (int i = 0; i < 16; ++i) {
        const int n = n0 + rg * 16 + i;
        if (n < N_NODES) {
            G[(size_t)n * C_OUT + d]   = accG[i];
            out[(size_t)n * C_OUT + d] = wsd * accG[i] + accR[i] + cdd;
        }
    }
}

// ---------------------------------------------------------------------------
// Gather: out[n,d] += Ws[d] * sum_k G[neighbors[n,k], d]
// 2 rows per block of 256 threads; neighbor lists staged in LDS.
// ---------------------------------------------------------------------------
__global__ __launch_bounds__(256)
void pcg_gather(const int* __restrict__ neighbors,
                const float* __restrict__ G,
                const float* __restrict__ Ws,
                float* __restrict__ out) {
    const int t     = threadIdx.x;
    const int local = t >> 7;           // 0/1
    const int d     = t & (C_OUT - 1);
    const int n     = blockIdx.x * 2 + local;

    __shared__ int snb[2][K_NBR];
    if (t < 2 * K_NBR) {
        int nn = blockIdx.x * 2 + (t >> 4);
        snb[t >> 4][t & 15] =
            (nn < N_NODES) ? neighbors[(size_t)nn * K_NBR + (t & 15)] : 0;
    }
    __syncthreads();

    if (n >= N_NODES) return;
    float acc = 0.f;
#pragma unroll
    for (int k = 0; k < K_NBR; ++k)
        acc += G[(size_t)snb[local][k] * C_OUT + d];

    out[(size_t)n * C_OUT + d] += Ws[d] * acc;
}

// ---------------------------------------------------------------------------
extern "C" void kernel_launch(void* const* d_in, const int* in_sizes, int n_in,
                              void* d_out, int out_size, void* d_ws, size_t ws_size,
                              hipStream_t stream) {
    const float* ndata     = (const float*)d_in[0];
    const int*   neighbors = (const int*)  d_in[1];
    const float* W_lin     = (const float*)d_in[2];
    const float* b_lin     = (const float*)d_in[3];
    const float* weight    = (const float*)d_in[4];
    const float* bias      = (const float*)d_in[5];
    const float* W_res     = (const float*)d_in[6];
    const float* b_res     = (const float*)d_in[7];
    float* out = (float*)d_out;

    float* G  = (float*)d_ws;                        // [N, C_OUT] = 15.36 MB
    float* Ws = G + (size_t)N_NODES * C_OUT;         // [C_OUT]
    float* Cd = Ws + C_OUT;                          // [C_OUT]

    pcg_consts<<<1, 128, 0, stream>>>(weight, b_lin, bias, b_res, Ws, Cd);
    pcg_gemm<<<(N_NODES + BR - 1) / BR, 256, 0, stream>>>(
        ndata, W_lin, W_res, Ws, Cd, G, out);
    pcg_gather<<<(N_NODES + 1) / 2, 256, 0, stream>>>(neighbors, G, Ws, out);
}

// Round 2
// 57.679 us; speedup vs baseline: 2.2043x; 2.2043x over previous
//
#include <hip/hip_runtime.h>
#include <math.h>

#define N_NODES 30000
#define K_NBR   16
#define C_IN    256
#define C_OUT   128
#define KS      9
#define S_MB    17

typedef __attribute__((ext_vector_type(4))) float f32x4;
typedef __attribute__((ext_vector_type(8))) short bf16x8;

static __device__ __forceinline__ ushort f2bf(float f) {
    uint u = __builtin_bit_cast(uint, f);
    u += 0x7fffu + ((u >> 16) & 1u);          // round-to-nearest-even
    return (ushort)(u >> 16);
}

// ---------------------------------------------------------------------------
// Per-channel constants:  Ws[d] = sum_s weight[d, idx[s]]
//   Cd[d] = Ws[d]*((K+1)*b_lin[d] + P[d]) + bias[d] + b_res[d]
// ---------------------------------------------------------------------------
__global__ void pcg_consts(const float* __restrict__ weight,
                           const float* __restrict__ b_lin,
                           const float* __restrict__ bias,
                           const float* __restrict__ b_res,
                           float* __restrict__ Ws,
                           float* __restrict__ Cd) {
    int d = threadIdx.x;
    if (d >= C_OUT) return;
    float freq = powf(10000.0f, -(float)(d & ~1) / (float)C_OUT);
    float ws = 0.f, p = 0.f;
    for (int s = 0; s < S_MB; ++s) {
        int idx = (int)floorf((float)s * (9.0f / 17.0f));
        ws += weight[d * KS + idx];
        float ang = (float)idx * freq;
        p += (d & 1) ? cosf(ang) : sinf(ang);
    }
    Ws[d] = ws;
    Cd[d] = ws * ((float)(K_NBR + 1) * b_lin[d] + p) + bias[d] + b_res[d];
}

// ---------------------------------------------------------------------------
// MFMA GEMM: F[n][j] = ndata[n,:] . Wstack[j,:]  (bf16 out)
//   Wstack rows 0..127 = W_lin, 128..255 = W_res.
// Block: 64 rows x 256 cols, 4 waves (wave w -> cols w*64..w*64+63).
// A staged f32->bf16 into LDS in MFMA fragment-lane order:
//   frag(kc,rg) at short-offset (kc*4+rg)*512, lane l holds 8 bf16 at l*8:
//   row = rg*16 + (l&15), k = kc*32 + (l>>4)*8.
// B fragments read from global W (f32, L2-resident) + converted per use.
// ---------------------------------------------------------------------------
__global__ __launch_bounds__(256)
void pcg_mfma(const float* __restrict__ ndata,
              const float* __restrict__ W_lin,
              const float* __restrict__ W_res,
              ushort* __restrict__ F) {
    __shared__ short sA[16384];                // 64 rows x 256 k, bf16, 32 KB

    const int t  = threadIdx.x;
    const int n0 = blockIdx.x * 64;

    // ---- stage A tile (f32 -> bf16, fragment-lane order) ----
#pragma unroll
    for (int i = 0; i < 16; ++i) {
        const int v    = i * 256 + t;          // float4 index within 64x256 tile
        const int row  = v >> 6;
        const int k0   = (v & 63) * 4;
        float4 a = make_float4(0.f, 0.f, 0.f, 0.f);
        if (n0 + row < N_NODES)
            a = *reinterpret_cast<const float4*>(
                    &ndata[(size_t)(n0 + row) * C_IN + k0]);
        const int kc   = k0 >> 5;
        const int rg   = row >> 4;
        const int l    = (row & 15) | (((k0 >> 3) & 3) << 4);
        const int half = (k0 >> 2) & 1;
        uint2 w;
        w.x = (uint)f2bf(a.x) | ((uint)f2bf(a.y) << 16);
        w.y = (uint)f2bf(a.z) | ((uint)f2bf(a.w) << 16);
        *reinterpret_cast<uint2*>(&sA[(kc * 4 + rg) * 512 + l * 8 + half * 4]) = w;
    }
    __syncthreads();

    const int wave = t >> 6;
    const int l    = t & 63;
    const float* Wb = (wave < 2) ? W_lin : W_res;
    const int colb  = (wave & 1) * 64;         // within Wb: 0 or 64

    f32x4 acc[4][4] = {};                       // [rg][cg]

#pragma unroll
    for (int kc = 0; kc < 8; ++kc) {
        bf16x8 a[4];
#pragma unroll
        for (int rg = 0; rg < 4; ++rg)
            a[rg] = *reinterpret_cast<const bf16x8*>(
                        &sA[(kc * 4 + rg) * 512 + l * 8]);
        bf16x8 b[4];
#pragma unroll
        for (int cg = 0; cg < 4; ++cg) {
            const int col = colb + cg * 16 + (l & 15);
            const int k   = kc * 32 + (l >> 4) * 8;
            const float4 w0 = *reinterpret_cast<const float4*>(
                                  &Wb[(size_t)col * C_IN + k]);
            const float4 w1 = *reinterpret_cast<const float4*>(
                                  &Wb[(size_t)col * C_IN + k + 4]);
            bf16x8 bb;
            bb[0] = (short)f2bf(w0.x); bb[1] = (short)f2bf(w0.y);
            bb[2] = (short)f2bf(w0.z); bb[3] = (short)f2bf(w0.w);
            bb[4] = (short)f2bf(w1.x); bb[5] = (short)f2bf(w1.y);
            bb[6] = (short)f2bf(w1.z); bb[7] = (short)f2bf(w1.w);
            b[cg] = bb;
        }
#pragma unroll
        for (int rg = 0; rg < 4; ++rg)
#pragma unroll
            for (int cg = 0; cg < 4; ++cg)
                acc[rg][cg] = __builtin_amdgcn_mfma_f32_16x16x32_bf16(
                                  a[rg], b[cg], acc[rg][cg], 0, 0, 0);
    }

    // ---- epilogue: D layout col = lane&15, row = (lane>>4)*4 + reg ----
    const int colw = wave * 64 + (l & 15);
    const int rl   = (l >> 4) * 4;
#pragma unroll
    for (int rg = 0; rg < 4; ++rg) {
#pragma unroll
        for (int cg = 0; cg < 4; ++cg) {
            const int col = colw + cg * 16;
#pragma unroll
            for (int j = 0; j < 4; ++j) {
                const int row = n0 + rg * 16 + rl + j;
                if (row < N_NODES)
                    F[(size_t)row * 256 + col] = f2bf(acc[rg][cg][j]);
            }
        }
    }
}

// ---------------------------------------------------------------------------
// Gather + epilogue: out[n][d] = Ws[d]*(G[n][d] + sum_k G[nbr][d]) + R[n][d] + Cd[d]
// F row: ushorts 0..127 = G (bf16), 128..255 = R (bf16).
// 4 nodes per 256-thread block; lane (64/node) covers cols 2l, 2l+1.
// ---------------------------------------------------------------------------
__global__ __launch_bounds__(256)
void pcg_gather(const int* __restrict__ neighbors,
                const ushort* __restrict__ F,
                const float* __restrict__ Ws,
                const float* __restrict__ Cd,
                float* __restrict__ out) {
    __shared__ int snb[64];
    const int t = threadIdx.x;
    if (t < 64) snb[t] = neighbors[(size_t)blockIdx.x * 64 + t];
    __syncthreads();

    const int g = t >> 6;                      // node group 0..3
    const int l = t & 63;
    const int n = blockIdx.x * 4 + g;

    const ushort* Frow = F + (size_t)n * 256;
    uint u = *reinterpret_cast<const uint*>(&Frow[2 * l]);
    float a0 = __builtin_bit_cast(float, u << 16);
    float a1 = __builtin_bit_cast(float, u & 0xffff0000u);

#pragma unroll
    for (int k = 0; k < K_NBR; ++k) {
        const int m = snb[g * 16 + k];
        uint v = *reinterpret_cast<const uint*>(&F[(size_t)m * 256 + 2 * l]);
        a0 += __builtin_bit_cast(float, v << 16);
        a1 += __builtin_bit_cast(float, v & 0xffff0000u);
    }

    uint r = *reinterpret_cast<const uint*>(&Frow[128 + 2 * l]);
    float r0 = __builtin_bit_cast(float, r << 16);
    float r1 = __builtin_bit_cast(float, r & 0xffff0000u);

    float2 ws = *reinterpret_cast<const float2*>(&Ws[2 * l]);
    float2 cd = *reinterpret_cast<const float2*>(&Cd[2 * l]);

    float2 o;
    o.x = ws.x * a0 + r0 + cd.x;
    o.y = ws.y * a1 + r1 + cd.y;
    *reinterpret_cast<float2*>(&out[(size_t)n * C_OUT + 2 * l]) = o;
}

// ---------------------------------------------------------------------------
extern "C" void kernel_launch(void* const* d_in, const int* in_sizes, int n_in,
                              void* d_out, int out_size, void* d_ws, size_t ws_size,
                              hipStream_t stream) {
    const float* ndata     = (const float*)d_in[0];
    const int*   neighbors = (const int*)  d_in[1];
    const float* W_lin     = (const float*)d_in[2];
    const float* b_lin     = (const float*)d_in[3];
    const float* weight    = (const float*)d_in[4];
    const float* bias      = (const float*)d_in[5];
    const float* W_res     = (const float*)d_in[6];
    const float* b_res     = (const float*)d_in[7];
    float* out = (float*)d_out;

    ushort* F  = (ushort*)d_ws;                          // [N][256] bf16 = 15.36 MB
    float*  Ws = (float*)(F + (size_t)N_NODES * 256);    // [128]
    float*  Cd = Ws + C_OUT;                             // [128]

    pcg_consts<<<1, 128, 0, stream>>>(weight, b_lin, bias, b_res, Ws, Cd);
    pcg_mfma<<<(N_NODES + 63) / 64, 256, 0, stream>>>(ndata, W_lin, W_res, F);
    pcg_gather<<<N_NODES / 4, 256, 0, stream>>>(neighbors, F, Ws, Cd, out);
}

// Round 3
// 43.839 us; speedup vs baseline: 2.9002x; 1.3157x over previous
//
#include <hip/hip_runtime.h>
#include <math.h>

#define N_NODES 30000
#define K_NBR   16
#define C_IN    256
#define C_OUT   128
#define KS      9
#define S_MB    17

typedef __attribute__((ext_vector_type(4))) float f32x4;
typedef __attribute__((ext_vector_type(8))) short bf16x8;

static __device__ __forceinline__ ushort f2bf(float f) {
    uint u = __builtin_bit_cast(uint, f);
    u += 0x7fffu + ((u >> 16) & 1u);          // round-to-nearest-even
    return (ushort)(u >> 16);
}

// ---------------------------------------------------------------------------
// Prep: blocks 0..31 convert stacked W (rows 0..127 = W_lin, 128..255 = W_res)
// into fragment-ordered bf16 Bf so the GEMM's B-load is contiguous 16 B/lane:
//   tt = ((kc*16 + colhi)*4 + ksub)*16 + col_lo   (8192 threads x 8 bf16)
//   col = colhi*16+col_lo, k0 = kc*32+ksub*8, Bf[tt*8 .. tt*8+7] = W[col][k0..]
// Block 32 computes per-channel constants Ws/Cd.
// ---------------------------------------------------------------------------
__global__ __launch_bounds__(256)
void pcg_prep(const float* __restrict__ W_lin,
              const float* __restrict__ W_res,
              const float* __restrict__ weight,
              const float* __restrict__ b_lin,
              const float* __restrict__ bias,
              const float* __restrict__ b_res,
              ushort* __restrict__ Bf,
              float* __restrict__ Ws,
              float* __restrict__ Cd) {
    if (blockIdx.x == 32) {
        int d = threadIdx.x;
        if (d >= C_OUT) return;
        float freq = powf(10000.0f, -(float)(d & ~1) / (float)C_OUT);
        float ws = 0.f, p = 0.f;
        for (int s = 0; s < S_MB; ++s) {
            int idx = (int)floorf((float)s * (9.0f / 17.0f));
            ws += weight[d * KS + idx];
            float ang = (float)idx * freq;
            p += (d & 1) ? cosf(ang) : sinf(ang);
        }
        Ws[d] = ws;
        Cd[d] = ws * ((float)(K_NBR + 1) * b_lin[d] + p) + bias[d] + b_res[d];
        return;
    }
    const int tt     = blockIdx.x * 256 + threadIdx.x;   // 0..8191
    const int col_lo = tt & 15;
    const int ksub   = (tt >> 4) & 3;
    const int colhi  = (tt >> 6) & 15;
    const int kc     = tt >> 10;
    const int col    = colhi * 16 + col_lo;
    const int k0     = kc * 32 + ksub * 8;
    const float* Wr = (col < C_OUT)
        ? &W_lin[(size_t)col * C_IN + k0]
        : &W_res[(size_t)(col - C_OUT) * C_IN + k0];
    const float4 w0 = *reinterpret_cast<const float4*>(Wr);
    const float4 w1 = *reinterpret_cast<const float4*>(Wr + 4);
    ushort b[8] = { f2bf(w0.x), f2bf(w0.y), f2bf(w0.z), f2bf(w0.w),
                    f2bf(w1.x), f2bf(w1.y), f2bf(w1.z), f2bf(w1.w) };
    *reinterpret_cast<uint4*>(&Bf[(size_t)tt * 8]) =
        *reinterpret_cast<const uint4*>(b);
}

// ---------------------------------------------------------------------------
// MFMA GEMM: F[n][j] = ndata[n,:] . Wstack[j,:]  (bf16 out)
// Block: 64 rows x 256 cols, 4 waves (wave w -> cols w*64..w*64+63).
// A staged f32->bf16 into LDS in fragment-lane order; B fragments loaded
// directly from pre-converted Bf (contiguous 1 KB per wave-load, L2-resident).
// ---------------------------------------------------------------------------
__global__ __launch_bounds__(256)
void pcg_mfma(const float* __restrict__ ndata,
              const ushort* __restrict__ Bf,
              ushort* __restrict__ F) {
    __shared__ short sA[16384];                // 64 rows x 256 k, bf16, 32 KB

    const int t  = threadIdx.x;
    const int n0 = blockIdx.x * 64;

    // ---- stage A tile (f32 -> bf16, fragment-lane order) ----
#pragma unroll
    for (int i = 0; i < 16; ++i) {
        const int v    = i * 256 + t;          // float4 index within 64x256 tile
        const int row  = v >> 6;
        const int k0   = (v & 63) * 4;
        float4 a = make_float4(0.f, 0.f, 0.f, 0.f);
        if (n0 + row < N_NODES)
            a = *reinterpret_cast<const float4*>(
                    &ndata[(size_t)(n0 + row) * C_IN + k0]);
        const int kc   = k0 >> 5;
        const int rg   = row >> 4;
        const int l    = (row & 15) | (((k0 >> 3) & 3) << 4);
        const int half = (k0 >> 2) & 1;
        uint2 w;
        w.x = (uint)f2bf(a.x) | ((uint)f2bf(a.y) << 16);
        w.y = (uint)f2bf(a.z) | ((uint)f2bf(a.w) << 16);
        *reinterpret_cast<uint2*>(&sA[(kc * 4 + rg) * 512 + l * 8 + half * 4]) = w;
    }
    __syncthreads();

    const int wave = t >> 6;
    const int l    = t & 63;

    f32x4 acc[4][4] = {};                       // [rg][cg]

#pragma unroll
    for (int kc = 0; kc < 8; ++kc) {
        bf16x8 a[4];
#pragma unroll
        for (int rg = 0; rg < 4; ++rg)
            a[rg] = *reinterpret_cast<const bf16x8*>(
                        &sA[(kc * 4 + rg) * 512 + l * 8]);
        bf16x8 b[4];
#pragma unroll
        for (int cg = 0; cg < 4; ++cg)
            b[cg] = *reinterpret_cast<const bf16x8*>(
                        &Bf[((size_t)(kc * 16 + wave * 4 + cg) * 64 + l) * 8]);
#pragma unroll
        for (int rg = 0; rg < 4; ++rg)
#pragma unroll
            for (int cg = 0; cg < 4; ++cg)
                acc[rg][cg] = __builtin_amdgcn_mfma_f32_16x16x32_bf16(
                                  a[rg], b[cg], acc[rg][cg], 0, 0, 0);
    }

    // ---- epilogue: D layout col = lane&15, row = (lane>>4)*4 + reg ----
    const int colw = wave * 64 + (l & 15);
    const int rl   = (l >> 4) * 4;
#pragma unroll
    for (int rg = 0; rg < 4; ++rg) {
#pragma unroll
        for (int cg = 0; cg < 4; ++cg) {
            const int col = colw + cg * 16;
#pragma unroll
            for (int j = 0; j < 4; ++j) {
                const int row = n0 + rg * 16 + rl + j;
                if (row < N_NODES)
                    F[(size_t)row * 256 + col] = f2bf(acc[rg][cg][j]);
            }
        }
    }
}

// ---------------------------------------------------------------------------
// Gather + epilogue: out[n][d] = Ws[d]*(G[n][d] + sum_k G[nbr][d]) + R[n][d] + Cd[d]
// F row: ushorts 0..127 = G (bf16), 128..255 = R (bf16).
// ---------------------------------------------------------------------------
__global__ __launch_bounds__(256)
void pcg_gather(const int* __restrict__ neighbors,
                const ushort* __restrict__ F,
                const float* __restrict__ Ws,
                const float* __restrict__ Cd,
                float* __restrict__ out) {
    __shared__ int snb[64];
    const int t = threadIdx.x;
    if (t < 64) snb[t] = neighbors[(size_t)blockIdx.x * 64 + t];
    __syncthreads();

    const int g = t >> 6;                      // node group 0..3
    const int l = t & 63;
    const int n = blockIdx.x * 4 + g;

    const ushort* Frow = F + (size_t)n * 256;
    uint u = *reinterpret_cast<const uint*>(&Frow[2 * l]);
    float a0 = __builtin_bit_cast(float, u << 16);
    float a1 = __builtin_bit_cast(float, u & 0xffff0000u);

#pragma unroll
    for (int k = 0; k < K_NBR; ++k) {
        const int m = snb[g * 16 + k];
        uint v = *reinterpret_cast<const uint*>(&F[(size_t)m * 256 + 2 * l]);
        a0 += __builtin_bit_cast(float, v << 16);
        a1 += __builtin_bit_cast(float, v & 0xffff0000u);
    }

    uint r = *reinterpret_cast<const uint*>(&Frow[128 + 2 * l]);
    float r0 = __builtin_bit_cast(float, r << 16);
    float r1 = __builtin_bit_cast(float, r & 0xffff0000u);

    float2 ws = *reinterpret_cast<const float2*>(&Ws[2 * l]);
    float2 cd = *reinterpret_cast<const float2*>(&Cd[2 * l]);

    float2 o;
    o.x = ws.x * a0 + r0 + cd.x;
    o.y = ws.y * a1 + r1 + cd.y;
    *reinterpret_cast<float2*>(&out[(size_t)n * C_OUT + 2 * l]) = o;
}

// ---------------------------------------------------------------------------
extern "C" void kernel_launch(void* const* d_in, const int* in_sizes, int n_in,
                              void* d_out, int out_size, void* d_ws, size_t ws_size,
                              hipStream_t stream) {
    const float* ndata     = (const float*)d_in[0];
    const int*   neighbors = (const int*)  d_in[1];
    const float* W_lin     = (const float*)d_in[2];
    const float* b_lin     = (const float*)d_in[3];
    const float* weight    = (const float*)d_in[4];
    const float* bias      = (const float*)d_in[5];
    const float* W_res     = (const float*)d_in[6];
    const float* b_res     = (const float*)d_in[7];
    float* out = (float*)d_out;

    ushort* F  = (ushort*)d_ws;                          // [N][256] bf16 = 15.36 MB
    ushort* Bf = F + (size_t)N_NODES * 256;              // [8192][8] bf16 = 128 KB
    float*  Ws = (float*)(Bf + 65536);                   // [128]
    float*  Cd = Ws + C_OUT;                             // [128]

    pcg_prep<<<33, 256, 0, stream>>>(W_lin, W_res, weight, b_lin, bias, b_res,
                                     Bf, Ws, Cd);
    pcg_mfma<<<(N_NODES + 63) / 64, 256, 0, stream>>>(ndata, Bf, F);
    pcg_gather<<<N_NODES / 4, 256, 0, stream>>>(neighbors, F, Ws, Cd, out);
}